// Round 3
// baseline (800.888 us; speedup 1.0000x reference)
//
#include <hip/hip_runtime.h>
#include <hip/hip_bf16.h>
#include <cmath>

// Single persistent fused kernel (512 blocks x 256 thr) + 1 memset.
// Phases separated by device-scope grid barriers (atomic counter + threadfence):
//  A: weight fp32->bf16 (incl. norm-MLP weights) + stats(x) + zero stats2
//  B: convx1 (gamma-MLP in bf16 weights, normalize+transpose -> xb)
//  C: qkv GEMM (MFMA) -> q fp32 (pre-scaled), kv bf16 interleaved [pos][48][k4|v4]
//  D: neighborhood attention (XCD-local unit mapping)
//  E: proj GEMM + residual -> x2, fused per-channel sum/sumsq atomics
//  F: convx2
//  G: mlp1 GEMM (gelu, bf16 transposed out)
//  H: mlp2 GEMM + residual -> x2 (in-place)
// Residency proof: LDS 51.2KB -> >=2 blocks/CU at any VGPR<=256; 512 <= 2*256. No deadlock.

#define NPOS 4096
#define C_CH 192
#define NB   512

typedef __bf16 bf16x8 __attribute__((ext_vector_type(8)));
typedef __bf16 bf16x4 __attribute__((ext_vector_type(4)));
typedef float  f32x4  __attribute__((ext_vector_type(4)));

__device__ __forceinline__ float bflo(unsigned int u) {
    union { unsigned int i; float f; } c; c.i = u << 16; return c.f;
}
__device__ __forceinline__ float bfhi(unsigned int u) {
    union { unsigned int i; float f; } c; c.i = u & 0xffff0000u; return c.f;
}

__device__ __forceinline__ void grid_sync(unsigned* cnt, int idx) {
    __syncthreads();
    if (threadIdx.x == 0) {
        __threadfence();   // release: drain this block's writes device-wide
        __hip_atomic_fetch_add(cnt + idx, 1u, __ATOMIC_ACQ_REL, __HIP_MEMORY_SCOPE_AGENT);
        while (__hip_atomic_load(cnt + idx, __ATOMIC_ACQUIRE, __HIP_MEMORY_SCOPE_AGENT) < NB)
            __builtin_amdgcn_s_sleep(2);
        __threadfence();   // acquire: invalidate stale cached lines
    }
    __syncthreads();
}

// fp32 -> bf16, 1024 floats per unit (256 thr x float4)
__device__ __forceinline__ void conv_unit(const float* __restrict__ src,
                                          __bf16* __restrict__ dst, int base)
{
    int i = (base * 256 + (int)threadIdx.x) * 4;
    float4 v = *(const float4*)(src + i);
    bf16x4 o = { (__bf16)v.x, (__bf16)v.y, (__bf16)v.z, (__bf16)v.w };
    *(bf16x4*)(dst + i) = o;
}

// per-channel sum / sumsq of one channel (whole block)
__device__ void stats_unit(float* sm, const float* __restrict__ x,
                           float* __restrict__ sums, float* __restrict__ sumsq, int c)
{
    const float4* xc = (const float4*)(x + (size_t)c * NPOS);
    float a = 0.f, a2 = 0.f;
    for (int i = threadIdx.x; i < NPOS / 4; i += 256) {
        float4 v = xc[i];
        a  += v.x + v.y + v.z + v.w;
        a2 += v.x * v.x + v.y * v.y + v.z * v.z + v.w * v.w;
    }
    #pragma unroll
    for (int off = 32; off > 0; off >>= 1) {
        a  += __shfl_down(a, off);
        a2 += __shfl_down(a2, off);
    }
    float* ls = sm; float* ls2 = sm + 4;
    int wid = threadIdx.x >> 6;
    if ((threadIdx.x & 63) == 0) { ls[wid] = a; ls2[wid] = a2; }
    __syncthreads();
    if (threadIdx.x == 0) {
        float t = 0.f, t2 = 0.f;
        #pragma unroll
        for (int w = 0; w < 4; w++) { t += ls[w]; t2 += ls2[w]; }
        sums[c] = t; sumsq[c] = t2;
    }
    __syncthreads();   // sm reused by next unit iteration
}

// gamma-MLP (bf16 weights) + normalize + transpose 16 positions -> xb
__device__ void convx_body(float* sm, const float* __restrict__ x,
    const float* __restrict__ sums, const float* __restrict__ sumsq,
    const float* __restrict__ scale,
    const __bf16* __restrict__ w1b, const float* __restrict__ b1,
    const __bf16* __restrict__ w2b, const float* __restrict__ b2,
    __bf16* __restrict__ xb, int p0)
{
    float* stats = sm;           // 192
    float* h     = sm + 192;     // 384
    float* gsl   = sm + 576;     // 192
    float* lds   = sm + 768;     // 192*17
    int t = threadIdx.x;

    if (t < C_CH) stats[t] = sums[t] * (1.0f / (float)NPOS);
    __syncthreads();
    for (int j = t; j < 384; j += 256) {
        float acc = b1[j];
        const __bf16* wr = w1b + (size_t)j * C_CH;
        #pragma unroll 4
        for (int c = 0; c < C_CH; c += 8) {
            bf16x8 w8 = *(const bf16x8*)(wr + c);
            acc += (float)w8[0] * stats[c]     + (float)w8[1] * stats[c + 1]
                 + (float)w8[2] * stats[c + 2] + (float)w8[3] * stats[c + 3]
                 + (float)w8[4] * stats[c + 4] + (float)w8[5] * stats[c + 5]
                 + (float)w8[6] * stats[c + 6] + (float)w8[7] * stats[c + 7];
        }
        h[j] = fmaxf(acc, 0.0f);
    }
    __syncthreads();
    if (t < C_CH) {
        float acc = b2[t];
        const __bf16* wr = w2b + (size_t)t * 384;
        #pragma unroll 4
        for (int j = 0; j < 384; j += 8) {
            bf16x8 w8 = *(const bf16x8*)(wr + j);
            acc += (float)w8[0] * h[j]     + (float)w8[1] * h[j + 1]
                 + (float)w8[2] * h[j + 2] + (float)w8[3] * h[j + 3]
                 + (float)w8[4] * h[j + 4] + (float)w8[5] * h[j + 5]
                 + (float)w8[6] * h[j + 6] + (float)w8[7] * h[j + 7];
        }
        float g = 1.0f / (1.0f + __expf(-acc));
        float rms = sqrtf(sumsq[t] * (1.0f / (float)NPOS) + 1e-6f);
        gsl[t] = scale[t] * g / rms;
    }
    __syncthreads();
    for (int idx = t; idx < 192 * 4; idx += 256) {
        int row = idx >> 2, p4 = idx & 3;
        float4 v = *(const float4*)(x + (size_t)row * NPOS + p0 + p4 * 4);
        float g = gsl[row];
        lds[row * 17 + p4 * 4 + 0] = v.x * g;
        lds[row * 17 + p4 * 4 + 1] = v.y * g;
        lds[row * 17 + p4 * 4 + 2] = v.z * g;
        lds[row * 17 + p4 * 4 + 3] = v.w * g;
    }
    __syncthreads();
    for (int idx = t; idx < 48 * 16; idx += 256) {
        int c4 = idx >> 4, p = idx & 15;
        bf16x4 o;
        #pragma unroll
        for (int j = 0; j < 4; j++) o[j] = (__bf16)lds[(c4 * 4 + j) * 17 + p];
        *(bf16x4*)(xb + (size_t)(p0 + p) * 192 + c4 * 4) = o;
    }
    __syncthreads();
}

// one 64x64 MFMA GEMM tile; EPI: 0=qkv scatter, 2=resid add, 3=gelu bf16^T,
// 4=resid add + fused per-channel sum/sumsq atomics
template <int K, int EPI>
__device__ void gemm_tile(__bf16* al, __bf16* bl, int bx, int by,
    const __bf16* __restrict__ W, const float* __restrict__ bias,
    const __bf16* __restrict__ X, void* __restrict__ out,
    const float* __restrict__ resid, int M, __bf16* __restrict__ out_kv,
    float* __restrict__ s2sum, float* __restrict__ s2sq)
{
    constexpr int KC  = 192;
    constexpr int LDA = 200;
    int t    = threadIdx.x;
    int lane = t & 63;
    int wv   = t >> 6;
    int r16  = lane & 15;
    int quad = lane >> 4;
    int wvm  = wv >> 1;
    int wvn  = wv & 1;
    int mBase = by * 64;
    int nBase = bx * 64;

    f32x4 acc[2][2];
    #pragma unroll
    for (int i = 0; i < 2; i++)
        #pragma unroll
        for (int j = 0; j < 2; j++)
            acc[i][j] = (f32x4){0.f, 0.f, 0.f, 0.f};

    for (int k0 = 0; k0 < K; k0 += KC) {
        #pragma unroll
        for (int it = 0; it < 6; it++) {
            int c = it * 256 + t;
            int row = c / 24, off = c - row * 24;
            bf16x8 va = *(const bf16x8*)(W + (size_t)(mBase + row) * K + k0 + off * 8);
            *(bf16x8*)(al + row * LDA + off * 8) = va;
            bf16x8 vb = *(const bf16x8*)(X + (size_t)(nBase + row) * K + k0 + off * 8);
            *(bf16x8*)(bl + row * LDA + off * 8) = vb;
        }
        __syncthreads();
        #pragma unroll
        for (int ks = 0; ks < KC / 32; ks++) {
            bf16x8 a0 = *(const bf16x8*)(al + (wvm * 32 + r16) * LDA + ks * 32 + quad * 8);
            bf16x8 a1 = *(const bf16x8*)(al + (wvm * 32 + 16 + r16) * LDA + ks * 32 + quad * 8);
            bf16x8 b0 = *(const bf16x8*)(bl + (wvn * 32 + r16) * LDA + ks * 32 + quad * 8);
            bf16x8 b1 = *(const bf16x8*)(bl + (wvn * 32 + 16 + r16) * LDA + ks * 32 + quad * 8);
            acc[0][0] = __builtin_amdgcn_mfma_f32_16x16x32_bf16(a0, b0, acc[0][0], 0, 0, 0);
            acc[0][1] = __builtin_amdgcn_mfma_f32_16x16x32_bf16(a0, b1, acc[0][1], 0, 0, 0);
            acc[1][0] = __builtin_amdgcn_mfma_f32_16x16x32_bf16(a1, b0, acc[1][0], 0, 0, 0);
            acc[1][1] = __builtin_amdgcn_mfma_f32_16x16x32_bf16(a1, b1, acc[1][1], 0, 0, 0);
        }
        __syncthreads();
    }

    #pragma unroll
    for (int rt = 0; rt < 2; rt++) {
        int m0 = mBase + wvm * 32 + rt * 16 + quad * 4;
        float b0 = bias[m0], b1v = bias[m0 + 1], b2v = bias[m0 + 2], b3v = bias[m0 + 3];
        float ss[4] = {0.f, 0.f, 0.f, 0.f}, sq[4] = {0.f, 0.f, 0.f, 0.f};
        #pragma unroll
        for (int ct = 0; ct < 2; ct++) {
            int n = nBase + wvn * 32 + ct * 16 + r16;
            f32x4 a4 = acc[rt][ct];
            float g0 = a4[0] + b0, g1 = a4[1] + b1v, g2 = a4[2] + b2v, g3 = a4[3] + b3v;
            if (EPI == 0) {
                int sect = m0 / 192;
                int o0 = m0 - sect * 192;
                if (sect == 0) {
                    const float qs = 0.17677669529663687f;   // 32^-0.5 folded into q
                    *(float4*)((float*)out + (size_t)n * 192 + o0) =
                        make_float4(g0 * qs, g1 * qs, g2 * qs, g3 * qs);
                } else {
                    bf16x4 kvv = { (__bf16)g0, (__bf16)g1, (__bf16)g2, (__bf16)g3 };
                    *(bf16x4*)(out_kv + (size_t)n * 384 + (o0 >> 2) * 8 + (sect - 1) * 4) = kvv;
                }
            } else if (EPI == 2 || EPI == 4) {
                float* o = (float*)out;
                size_t i0 = (size_t)m0 * NPOS + n;
                float v0 = g0 + resid[i0];
                float v1 = g1 + resid[i0 + NPOS];
                float v2 = g2 + resid[i0 + 2 * NPOS];
                float v3 = g3 + resid[i0 + 3 * NPOS];
                o[i0] = v0; o[i0 + NPOS] = v1; o[i0 + 2 * NPOS] = v2; o[i0 + 3 * NPOS] = v3;
                if (EPI == 4) {
                    ss[0] += v0; sq[0] += v0 * v0;
                    ss[1] += v1; sq[1] += v1 * v1;
                    ss[2] += v2; sq[2] += v2 * v2;
                    ss[3] += v3; sq[3] += v3 * v3;
                }
            } else {
                bf16x4 v;
                v[0] = (__bf16)(0.5f * g0 * (1.0f + erff(g0 * 0.7071067811865475f)));
                v[1] = (__bf16)(0.5f * g1 * (1.0f + erff(g1 * 0.7071067811865475f)));
                v[2] = (__bf16)(0.5f * g2 * (1.0f + erff(g2 * 0.7071067811865475f)));
                v[3] = (__bf16)(0.5f * g3 * (1.0f + erff(g3 * 0.7071067811865475f)));
                *(bf16x4*)((__bf16*)out + (size_t)n * M + m0) = v;
            }
        }
        if (EPI == 4) {
            #pragma unroll
            for (int j = 0; j < 4; j++) {
                float s = ss[j], s2v = sq[j];
                #pragma unroll
                for (int off = 8; off >= 1; off >>= 1) {
                    s   += __shfl_down(s, off);
                    s2v += __shfl_down(s2v, off);
                }
                if (r16 == 0) {
                    atomicAdd(&s2sum[m0 + j], s);
                    atomicAdd(&s2sq[m0 + j], s2v);
                }
            }
        }
    }
}

// one attention unit = 8 (pos,head) pairs over the block's 256 threads
__device__ __forceinline__ void attn_unit(const float* __restrict__ q,
    const __bf16* __restrict__ kv, __bf16* __restrict__ o, int unit)
{
    int t = threadIdx.x;
    int pairIdx = unit * 8 + (t >> 5);
    int sg   = (t >> 3) & 3;
    int lane = t & 7;
    int pos = pairIdx / 6;
    int head = pairIdx - pos * 6;
    int wq = pos & 15;
    int hq = (pos >> 4) & 15;
    int dq = pos >> 8;
    int d0 = min(max(dq - 2, 0), 11);
    int h0 = min(max(hq - 2, 0), 11);
    int w0 = min(max(wq - 2, 0), 11);

    const __bf16* kvb = kv + head * 64 + lane * 8;
    float4 q4 = *(const float4*)(q + (size_t)pos * 192 + head * 32 + lane * 4);

    float l = 0.0f;
    float4 acc = make_float4(0.f, 0.f, 0.f, 0.f);

    for (int dh = sg; dh < 25; dh += 4) {
        int di = dh / 5;
        int hi = dh - di * 5;
        int np0 = (d0 + di) * 256 + (h0 + hi) * 16 + w0;
        const __bf16* p = kvb + (size_t)np0 * 384;
        #pragma unroll
        for (int wi = 0; wi < 5; wi++) {
            uint4 u = *(const uint4*)p;
            float s = q4.x * bflo(u.x) + q4.y * bfhi(u.x)
                    + q4.z * bflo(u.y) + q4.w * bfhi(u.y);
            s += __shfl_xor(s, 1);
            s += __shfl_xor(s, 2);
            s += __shfl_xor(s, 4);
            float pr = __expf(s);
            l += pr;
            acc.x += pr * bflo(u.z);
            acc.y += pr * bfhi(u.z);
            acc.z += pr * bflo(u.w);
            acc.w += pr * bfhi(u.w);
            p += 384;
        }
    }

    #pragma unroll
    for (int off = 8; off <= 16; off <<= 1) {
        l     += __shfl_xor(l, off);
        acc.x += __shfl_xor(acc.x, off);
        acc.y += __shfl_xor(acc.y, off);
        acc.z += __shfl_xor(acc.z, off);
        acc.w += __shfl_xor(acc.w, off);
    }

    if (sg == 0) {
        float rl = 1.0f / l;
        bf16x4 ov = { (__bf16)(acc.x * rl), (__bf16)(acc.y * rl),
                      (__bf16)(acc.z * rl), (__bf16)(acc.w * rl) };
        *(bf16x4*)(o + (size_t)pos * 192 + head * 32 + lane * 4) = ov;
    }
}

__global__ __launch_bounds__(256) void fused(
    const float* __restrict__ x, const float* __restrict__ scale1,
    const float* __restrict__ n1_w1, const float* __restrict__ n1_b1,
    const float* __restrict__ n1_w2, const float* __restrict__ n1_b2,
    const float* __restrict__ qkv_w, const float* __restrict__ qkv_b,
    const float* __restrict__ proj_w, const float* __restrict__ proj_b,
    const float* __restrict__ scale2,
    const float* __restrict__ n2_w1, const float* __restrict__ n2_b1,
    const float* __restrict__ n2_w2, const float* __restrict__ n2_b2,
    const float* __restrict__ mlp_w1, const float* __restrict__ mlp_b1,
    const float* __restrict__ mlp_w2, const float* __restrict__ mlp_b2,
    float* __restrict__ ws, float* __restrict__ x2)
{
    __shared__ __align__(16) char smraw[51200];   // GEMM al|bl; convx/stats reuse
    __bf16* al  = (__bf16*)smraw;
    __bf16* bl  = al + 64 * 200;
    float*  smf = (float*)smraw;

    float*  q_buf   = ws;
    __bf16* kv_buf  = (__bf16*)(ws + 786432);
    __bf16* m_buf   = (__bf16*)ws;                 // aliases q+kv (dead after attn)
    __bf16* xb      = (__bf16*)(ws + 2359296);
    __bf16* o_attn  = (__bf16*)(ws + 2752512);
    __bf16* qkv_wb  = (__bf16*)(ws + 3145728);
    __bf16* proj_wb = qkv_wb + 110592;
    __bf16* m1_wb   = proj_wb + 36864;
    __bf16* m2_wb   = m1_wb + 147456;
    float*  sums1   = ws + 3366912;
    float*  sumsq1  = ws + 3367104;
    float*  sums2   = ws + 3367296;
    float*  sumsq2  = ws + 3367488;
    __bf16* n1w1b   = (__bf16*)(ws + 3367680);
    __bf16* n1w2b   = n1w1b + 73728;
    __bf16* n2w1b   = n1w2b + 73728;
    __bf16* n2w2b   = n2w1b + 73728;
    unsigned* bar   = (unsigned*)(ws + 3515136);

    int bid = blockIdx.x;
    int t   = threadIdx.x;

    // ---- phase A: weight conversions + stats(x) + zero stats2 ----
    for (int u = bid; u < 913; u += NB) {
        if      (u < 108) conv_unit(qkv_w,  qkv_wb, u);
        else if (u < 144) conv_unit(proj_w, proj_wb, u - 108);
        else if (u < 288) conv_unit(mlp_w1, m1_wb, u - 144);
        else if (u < 432) conv_unit(mlp_w2, m2_wb, u - 288);
        else if (u < 504) conv_unit(n1_w1,  n1w1b, u - 432);
        else if (u < 576) conv_unit(n1_w2,  n1w2b, u - 504);
        else if (u < 648) conv_unit(n2_w1,  n2w1b, u - 576);
        else if (u < 720) conv_unit(n2_w2,  n2w2b, u - 648);
        else if (u < 912) stats_unit(smf, x, sums1, sumsq1, u - 720);
        else { if (t < 192) { sums2[t] = 0.f; sumsq2[t] = 0.f; } }
    }
    grid_sync(bar, 0);

    // ---- phase B: convx1 ----
    if (bid < 256)
        convx_body(smf, x, sums1, sumsq1, scale1, n1w1b, n1_b1, n1w2b, n1_b2, xb, bid * 16);
    grid_sync(bar, 1);

    // ---- phase C: qkv GEMM (576 tiles) ----
    for (int tile = bid; tile < 576; tile += NB)
        gemm_tile<192, 0>(al, bl, tile & 63, tile >> 6, qkv_wb, qkv_b, xb,
                          (void*)q_buf, nullptr, 576, kv_buf, nullptr, nullptr);
    grid_sync(bar, 2);

    // ---- phase D: attention (XCD-local mapping: block b -> XCD b%8 slab) ----
    {
        int base = (bid & 7) * 384 + (bid >> 3) * 6;
        for (int i = 0; i < 6; i++)
            attn_unit(q_buf, kv_buf, o_attn, base + i);
    }
    grid_sync(bar, 3);

    // ---- phase E: proj GEMM + residual + fused stats atomics (192 tiles) ----
    if (bid < 192)
        gemm_tile<192, 4>(al, bl, bid & 63, bid >> 6, proj_wb, proj_b, o_attn,
                          (void*)x2, x, 192, nullptr, sums2, sumsq2);
    grid_sync(bar, 4);

    // ---- phase F: convx2 ----
    if (bid < 256)
        convx_body(smf, x2, sums2, sumsq2, scale2, n2w1b, n2_b1, n2w2b, n2_b2, xb, bid * 16);
    grid_sync(bar, 5);

    // ---- phase G: mlp1 GEMM (768 tiles, gelu -> m_buf bf16^T) ----
    for (int tile = bid; tile < 768; tile += NB)
        gemm_tile<192, 3>(al, bl, tile & 63, tile >> 6, m1_wb, mlp_b1, xb,
                          (void*)m_buf, nullptr, 768, nullptr, nullptr, nullptr);
    grid_sync(bar, 6);

    // ---- phase H: mlp2 GEMM + residual (in-place x2) ----
    if (bid < 192)
        gemm_tile<768, 2>(al, bl, bid & 63, bid >> 6, m2_wb, mlp_b2, m_buf,
                          (void*)x2, x2, 192, nullptr, nullptr, nullptr);
}

// ---------------------------------------------------------------------------
extern "C" void kernel_launch(void* const* d_in, const int* in_sizes, int n_in,
                              void* d_out, int out_size, void* d_ws, size_t ws_size,
                              hipStream_t stream)
{
    const float* x      = (const float*)d_in[0];
    const float* scale1 = (const float*)d_in[1];
    const float* n1_w1  = (const float*)d_in[2];
    const float* n1_b1  = (const float*)d_in[3];
    const float* n1_w2  = (const float*)d_in[4];
    const float* n1_b2  = (const float*)d_in[5];
    const float* qkv_w  = (const float*)d_in[6];
    const float* qkv_b  = (const float*)d_in[7];
    const float* proj_w = (const float*)d_in[8];
    const float* proj_b = (const float*)d_in[9];
    const float* scale2 = (const float*)d_in[10];
    const float* n2_w1  = (const float*)d_in[11];
    const float* n2_b1  = (const float*)d_in[12];
    const float* n2_w2  = (const float*)d_in[13];
    const float* n2_b2  = (const float*)d_in[14];
    const float* mlp_w1 = (const float*)d_in[15];
    const float* mlp_b1 = (const float*)d_in[16];
    const float* mlp_w2 = (const float*)d_in[17];
    const float* mlp_b2 = (const float*)d_in[18];

    float* ws = (float*)d_ws;
    float* x2 = (float*)d_out;

    // zero the 16 barrier counters (re-executed on every graph replay)
    hipMemsetAsync(ws + 3515136, 0, 64, stream);

    fused<<<NB, 256, 0, stream>>>(x, scale1, n1_w1, n1_b1, n1_w2, n1_b2,
                                  qkv_w, qkv_b, proj_w, proj_b,
                                  scale2, n2_w1, n2_b1, n2_w2, n2_b2,
                                  mlp_w1, mlp_b1, mlp_w2, mlp_b2,
                                  ws, x2);
}

// Round 4
// 454.085 us; speedup vs baseline: 1.7637x; 1.7637x over previous
//
#include <hip/hip_runtime.h>
#include <hip/hip_bf16.h>
#include <cmath>

// Single persistent fused kernel (512 blocks x 256 thr) + 1 tiny memset.
// Phases separated by device-scope grid barriers.
// BARRIER FIX vs R3: poll with RELAXED atomic loads (no per-poll buffer_inv);
// RELEASE on the fetch_add (one L2 writeback); ONE ACQUIRE load after the
// spin exits (one invalidate). R3 polled with ACQUIRE -> invalidate storm.
//  A: weight fp32->bf16 (incl. norm-MLP weights) + stats(x) + zero stats2
//  B: convx1   C: qkv GEMM   D: attention   E: proj GEMM + resid + stats atomics
//  F: convx2   G: mlp1 GEMM  H: mlp2 GEMM + resid
// Residency: LDS 50KB -> >=2 blocks/CU at any VGPR<=256; 512 <= 2*256 CUs.

#define NPOS 4096
#define C_CH 192
#define NB   512

typedef __bf16 bf16x8 __attribute__((ext_vector_type(8)));
typedef __bf16 bf16x4 __attribute__((ext_vector_type(4)));
typedef float  f32x4  __attribute__((ext_vector_type(4)));

__device__ __forceinline__ float bflo(unsigned int u) {
    union { unsigned int i; float f; } c; c.i = u << 16; return c.f;
}
__device__ __forceinline__ float bfhi(unsigned int u) {
    union { unsigned int i; float f; } c; c.i = u & 0xffff0000u; return c.f;
}

__device__ __forceinline__ void grid_sync(unsigned* cnt, int idx) {
    __syncthreads();
    if (threadIdx.x == 0) {
        // release: one L2 writeback, then signal arrival
        __hip_atomic_fetch_add(cnt + idx, 1u, __ATOMIC_RELEASE, __HIP_MEMORY_SCOPE_AGENT);
        // spin with RELAXED loads: coherent-point reads, NO cache maintenance
        while (__hip_atomic_load(cnt + idx, __ATOMIC_RELAXED, __HIP_MEMORY_SCOPE_AGENT) < NB)
            __builtin_amdgcn_s_sleep(2);
        // acquire ONCE: single invalidate so we see other XCDs' phase writes
        (void)__hip_atomic_load(cnt + idx, __ATOMIC_ACQUIRE, __HIP_MEMORY_SCOPE_AGENT);
    }
    __syncthreads();
}

// fp32 -> bf16, 1024 floats per unit (256 thr x float4)
__device__ __forceinline__ void conv_unit(const float* __restrict__ src,
                                          __bf16* __restrict__ dst, int base)
{
    int i = (base * 256 + (int)threadIdx.x) * 4;
    float4 v = *(const float4*)(src + i);
    bf16x4 o = { (__bf16)v.x, (__bf16)v.y, (__bf16)v.z, (__bf16)v.w };
    *(bf16x4*)(dst + i) = o;
}

// per-channel sum / sumsq of one channel (whole block)
__device__ void stats_unit(float* sm, const float* __restrict__ x,
                           float* __restrict__ sums, float* __restrict__ sumsq, int c)
{
    const float4* xc = (const float4*)(x + (size_t)c * NPOS);
    float a = 0.f, a2 = 0.f;
    for (int i = threadIdx.x; i < NPOS / 4; i += 256) {
        float4 v = xc[i];
        a  += v.x + v.y + v.z + v.w;
        a2 += v.x * v.x + v.y * v.y + v.z * v.z + v.w * v.w;
    }
    #pragma unroll
    for (int off = 32; off > 0; off >>= 1) {
        a  += __shfl_down(a, off);
        a2 += __shfl_down(a2, off);
    }
    float* ls = sm; float* ls2 = sm + 4;
    int wid = threadIdx.x >> 6;
    if ((threadIdx.x & 63) == 0) { ls[wid] = a; ls2[wid] = a2; }
    __syncthreads();
    if (threadIdx.x == 0) {
        float t = 0.f, t2 = 0.f;
        #pragma unroll
        for (int w = 0; w < 4; w++) { t += ls[w]; t2 += ls2[w]; }
        sums[c] = t; sumsq[c] = t2;
    }
    __syncthreads();   // sm reused by next unit iteration
}

// gamma-MLP (bf16 weights) + normalize + transpose 16 positions -> xb
__device__ void convx_body(float* sm, const float* __restrict__ x,
    const float* __restrict__ sums, const float* __restrict__ sumsq,
    const float* __restrict__ scale,
    const __bf16* __restrict__ w1b, const float* __restrict__ b1,
    const __bf16* __restrict__ w2b, const float* __restrict__ b2,
    __bf16* __restrict__ xb, int p0)
{
    float* stats = sm;           // 192
    float* h     = sm + 192;     // 384
    float* gsl   = sm + 576;     // 192
    float* lds   = sm + 768;     // 192*17
    int t = threadIdx.x;

    if (t < C_CH) stats[t] = sums[t] * (1.0f / (float)NPOS);
    __syncthreads();
    for (int j = t; j < 384; j += 256) {
        float acc = b1[j];
        const __bf16* wr = w1b + (size_t)j * C_CH;
        #pragma unroll 4
        for (int c = 0; c < C_CH; c += 8) {
            bf16x8 w8 = *(const bf16x8*)(wr + c);
            acc += (float)w8[0] * stats[c]     + (float)w8[1] * stats[c + 1]
                 + (float)w8[2] * stats[c + 2] + (float)w8[3] * stats[c + 3]
                 + (float)w8[4] * stats[c + 4] + (float)w8[5] * stats[c + 5]
                 + (float)w8[6] * stats[c + 6] + (float)w8[7] * stats[c + 7];
        }
        h[j] = fmaxf(acc, 0.0f);
    }
    __syncthreads();
    if (t < C_CH) {
        float acc = b2[t];
        const __bf16* wr = w2b + (size_t)t * 384;
        #pragma unroll 4
        for (int j = 0; j < 384; j += 8) {
            bf16x8 w8 = *(const bf16x8*)(wr + j);
            acc += (float)w8[0] * h[j]     + (float)w8[1] * h[j + 1]
                 + (float)w8[2] * h[j + 2] + (float)w8[3] * h[j + 3]
                 + (float)w8[4] * h[j + 4] + (float)w8[5] * h[j + 5]
                 + (float)w8[6] * h[j + 6] + (float)w8[7] * h[j + 7];
        }
        float g = 1.0f / (1.0f + __expf(-acc));
        float rms = sqrtf(sumsq[t] * (1.0f / (float)NPOS) + 1e-6f);
        gsl[t] = scale[t] * g / rms;
    }
    __syncthreads();
    for (int idx = t; idx < 192 * 4; idx += 256) {
        int row = idx >> 2, p4 = idx & 3;
        float4 v = *(const float4*)(x + (size_t)row * NPOS + p0 + p4 * 4);
        float g = gsl[row];
        lds[row * 17 + p4 * 4 + 0] = v.x * g;
        lds[row * 17 + p4 * 4 + 1] = v.y * g;
        lds[row * 17 + p4 * 4 + 2] = v.z * g;
        lds[row * 17 + p4 * 4 + 3] = v.w * g;
    }
    __syncthreads();
    for (int idx = t; idx < 48 * 16; idx += 256) {
        int c4 = idx >> 4, p = idx & 15;
        bf16x4 o;
        #pragma unroll
        for (int j = 0; j < 4; j++) o[j] = (__bf16)lds[(c4 * 4 + j) * 17 + p];
        *(bf16x4*)(xb + (size_t)(p0 + p) * 192 + c4 * 4) = o;
    }
    __syncthreads();
}

// one 64x64 MFMA GEMM tile; EPI: 0=qkv scatter, 2=resid add, 3=gelu bf16^T,
// 4=resid add + fused per-channel sum/sumsq atomics
template <int K, int EPI>
__device__ void gemm_tile(__bf16* al, __bf16* bl, int bx, int by,
    const __bf16* __restrict__ W, const float* __restrict__ bias,
    const __bf16* __restrict__ X, void* __restrict__ out,
    const float* __restrict__ resid, int M, __bf16* __restrict__ out_kv,
    float* __restrict__ s2sum, float* __restrict__ s2sq)
{
    constexpr int KC  = 192;
    constexpr int LDA = 200;
    int t    = threadIdx.x;
    int lane = t & 63;
    int wv   = t >> 6;
    int r16  = lane & 15;
    int quad = lane >> 4;
    int wvm  = wv >> 1;
    int wvn  = wv & 1;
    int mBase = by * 64;
    int nBase = bx * 64;

    f32x4 acc[2][2];
    #pragma unroll
    for (int i = 0; i < 2; i++)
        #pragma unroll
        for (int j = 0; j < 2; j++)
            acc[i][j] = (f32x4){0.f, 0.f, 0.f, 0.f};

    for (int k0 = 0; k0 < K; k0 += KC) {
        #pragma unroll
        for (int it = 0; it < 6; it++) {
            int c = it * 256 + t;
            int row = c / 24, off = c - row * 24;
            bf16x8 va = *(const bf16x8*)(W + (size_t)(mBase + row) * K + k0 + off * 8);
            *(bf16x8*)(al + row * LDA + off * 8) = va;
            bf16x8 vb = *(const bf16x8*)(X + (size_t)(nBase + row) * K + k0 + off * 8);
            *(bf16x8*)(bl + row * LDA + off * 8) = vb;
        }
        __syncthreads();
        #pragma unroll
        for (int ks = 0; ks < KC / 32; ks++) {
            bf16x8 a0 = *(const bf16x8*)(al + (wvm * 32 + r16) * LDA + ks * 32 + quad * 8);
            bf16x8 a1 = *(const bf16x8*)(al + (wvm * 32 + 16 + r16) * LDA + ks * 32 + quad * 8);
            bf16x8 b0 = *(const bf16x8*)(bl + (wvn * 32 + r16) * LDA + ks * 32 + quad * 8);
            bf16x8 b1 = *(const bf16x8*)(bl + (wvn * 32 + 16 + r16) * LDA + ks * 32 + quad * 8);
            acc[0][0] = __builtin_amdgcn_mfma_f32_16x16x32_bf16(a0, b0, acc[0][0], 0, 0, 0);
            acc[0][1] = __builtin_amdgcn_mfma_f32_16x16x32_bf16(a0, b1, acc[0][1], 0, 0, 0);
            acc[1][0] = __builtin_amdgcn_mfma_f32_16x16x32_bf16(a1, b0, acc[1][0], 0, 0, 0);
            acc[1][1] = __builtin_amdgcn_mfma_f32_16x16x32_bf16(a1, b1, acc[1][1], 0, 0, 0);
        }
        __syncthreads();
    }

    #pragma unroll
    for (int rt = 0; rt < 2; rt++) {
        int m0 = mBase + wvm * 32 + rt * 16 + quad * 4;
        float b0 = bias[m0], b1v = bias[m0 + 1], b2v = bias[m0 + 2], b3v = bias[m0 + 3];
        float ss[4] = {0.f, 0.f, 0.f, 0.f}, sq[4] = {0.f, 0.f, 0.f, 0.f};
        #pragma unroll
        for (int ct = 0; ct < 2; ct++) {
            int n = nBase + wvn * 32 + ct * 16 + r16;
            f32x4 a4 = acc[rt][ct];
            float g0 = a4[0] + b0, g1 = a4[1] + b1v, g2 = a4[2] + b2v, g3 = a4[3] + b3v;
            if (EPI == 0) {
                int sect = m0 / 192;
                int o0 = m0 - sect * 192;
                if (sect == 0) {
                    const float qs = 0.17677669529663687f;   // 32^-0.5 folded into q
                    *(float4*)((float*)out + (size_t)n * 192 + o0) =
                        make_float4(g0 * qs, g1 * qs, g2 * qs, g3 * qs);
                } else {
                    bf16x4 kvv = { (__bf16)g0, (__bf16)g1, (__bf16)g2, (__bf16)g3 };
                    *(bf16x4*)(out_kv + (size_t)n * 384 + (o0 >> 2) * 8 + (sect - 1) * 4) = kvv;
                }
            } else if (EPI == 2 || EPI == 4) {
                float* o = (float*)out;
                size_t i0 = (size_t)m0 * NPOS + n;
                float v0 = g0 + resid[i0];
                float v1 = g1 + resid[i0 + NPOS];
                float v2 = g2 + resid[i0 + 2 * NPOS];
                float v3 = g3 + resid[i0 + 3 * NPOS];
                o[i0] = v0; o[i0 + NPOS] = v1; o[i0 + 2 * NPOS] = v2; o[i0 + 3 * NPOS] = v3;
                if (EPI == 4) {
                    ss[0] += v0; sq[0] += v0 * v0;
                    ss[1] += v1; sq[1] += v1 * v1;
                    ss[2] += v2; sq[2] += v2 * v2;
                    ss[3] += v3; sq[3] += v3 * v3;
                }
            } else {
                bf16x4 v;
                v[0] = (__bf16)(0.5f * g0 * (1.0f + erff(g0 * 0.7071067811865475f)));
                v[1] = (__bf16)(0.5f * g1 * (1.0f + erff(g1 * 0.7071067811865475f)));
                v[2] = (__bf16)(0.5f * g2 * (1.0f + erff(g2 * 0.7071067811865475f)));
                v[3] = (__bf16)(0.5f * g3 * (1.0f + erff(g3 * 0.7071067811865475f)));
                *(bf16x4*)((__bf16*)out + (size_t)n * M + m0) = v;
            }
        }
        if (EPI == 4) {
            #pragma unroll
            for (int j = 0; j < 4; j++) {
                float s = ss[j], s2v = sq[j];
                #pragma unroll
                for (int off = 8; off >= 1; off >>= 1) {
                    s   += __shfl_down(s, off);
                    s2v += __shfl_down(s2v, off);
                }
                if (r16 == 0) {
                    atomicAdd(&s2sum[m0 + j], s);
                    atomicAdd(&s2sq[m0 + j], s2v);
                }
            }
        }
    }
}

// one attention unit = 8 (pos,head) pairs over the block's 256 threads
__device__ __forceinline__ void attn_unit(const float* __restrict__ q,
    const __bf16* __restrict__ kv, __bf16* __restrict__ o, int unit)
{
    int t = threadIdx.x;
    int pairIdx = unit * 8 + (t >> 5);
    int sg   = (t >> 3) & 3;
    int lane = t & 7;
    int pos = pairIdx / 6;
    int head = pairIdx - pos * 6;
    int wq = pos & 15;
    int hq = (pos >> 4) & 15;
    int dq = pos >> 8;
    int d0 = min(max(dq - 2, 0), 11);
    int h0 = min(max(hq - 2, 0), 11);
    int w0 = min(max(wq - 2, 0), 11);

    const __bf16* kvb = kv + head * 64 + lane * 8;
    float4 q4 = *(const float4*)(q + (size_t)pos * 192 + head * 32 + lane * 4);

    float l = 0.0f;
    float4 acc = make_float4(0.f, 0.f, 0.f, 0.f);

    for (int dh = sg; dh < 25; dh += 4) {
        int di = dh / 5;
        int hi = dh - di * 5;
        int np0 = (d0 + di) * 256 + (h0 + hi) * 16 + w0;
        const __bf16* p = kvb + (size_t)np0 * 384;
        #pragma unroll
        for (int wi = 0; wi < 5; wi++) {
            uint4 u = *(const uint4*)p;
            float s = q4.x * bflo(u.x) + q4.y * bfhi(u.x)
                    + q4.z * bflo(u.y) + q4.w * bfhi(u.y);
            s += __shfl_xor(s, 1);
            s += __shfl_xor(s, 2);
            s += __shfl_xor(s, 4);
            float pr = __expf(s);
            l += pr;
            acc.x += pr * bflo(u.z);
            acc.y += pr * bfhi(u.z);
            acc.z += pr * bflo(u.w);
            acc.w += pr * bfhi(u.w);
            p += 384;
        }
    }

    #pragma unroll
    for (int off = 8; off <= 16; off <<= 1) {
        l     += __shfl_xor(l, off);
        acc.x += __shfl_xor(acc.x, off);
        acc.y += __shfl_xor(acc.y, off);
        acc.z += __shfl_xor(acc.z, off);
        acc.w += __shfl_xor(acc.w, off);
    }

    if (sg == 0) {
        float rl = 1.0f / l;
        bf16x4 ov = { (__bf16)(acc.x * rl), (__bf16)(acc.y * rl),
                      (__bf16)(acc.z * rl), (__bf16)(acc.w * rl) };
        *(bf16x4*)(o + (size_t)pos * 192 + head * 32 + lane * 4) = ov;
    }
}

__global__ __launch_bounds__(256) void fused(
    const float* __restrict__ x, const float* __restrict__ scale1,
    const float* __restrict__ n1_w1, const float* __restrict__ n1_b1,
    const float* __restrict__ n1_w2, const float* __restrict__ n1_b2,
    const float* __restrict__ qkv_w, const float* __restrict__ qkv_b,
    const float* __restrict__ proj_w, const float* __restrict__ proj_b,
    const float* __restrict__ scale2,
    const float* __restrict__ n2_w1, const float* __restrict__ n2_b1,
    const float* __restrict__ n2_w2, const float* __restrict__ n2_b2,
    const float* __restrict__ mlp_w1, const float* __restrict__ mlp_b1,
    const float* __restrict__ mlp_w2, const float* __restrict__ mlp_b2,
    float* __restrict__ ws, float* __restrict__ x2)
{
    __shared__ __align__(16) char smraw[51200];   // GEMM al|bl; convx/stats reuse
    __bf16* al  = (__bf16*)smraw;
    __bf16* bl  = al + 64 * 200;
    float*  smf = (float*)smraw;

    float*  q_buf   = ws;
    __bf16* kv_buf  = (__bf16*)(ws + 786432);
    __bf16* m_buf   = (__bf16*)ws;                 // aliases q+kv (dead after attn)
    __bf16* xb      = (__bf16*)(ws + 2359296);
    __bf16* o_attn  = (__bf16*)(ws + 2752512);
    __bf16* qkv_wb  = (__bf16*)(ws + 3145728);
    __bf16* proj_wb = qkv_wb + 110592;
    __bf16* m1_wb   = proj_wb + 36864;
    __bf16* m2_wb   = m1_wb + 147456;
    float*  sums1   = ws + 3366912;
    float*  sumsq1  = ws + 3367104;
    float*  sums2   = ws + 3367296;
    float*  sumsq2  = ws + 3367488;
    __bf16* n1w1b   = (__bf16*)(ws + 3367680);
    __bf16* n1w2b   = n1w1b + 73728;
    __bf16* n2w1b   = n1w2b + 73728;
    __bf16* n2w2b   = n2w1b + 73728;
    unsigned* bar   = (unsigned*)(ws + 3515136);

    int bid = blockIdx.x;
    int t   = threadIdx.x;

    // ---- phase A: weight conversions + stats(x) + zero stats2 ----
    for (int u = bid; u < 913; u += NB) {
        if      (u < 108) conv_unit(qkv_w,  qkv_wb, u);
        else if (u < 144) conv_unit(proj_w, proj_wb, u - 108);
        else if (u < 288) conv_unit(mlp_w1, m1_wb, u - 144);
        else if (u < 432) conv_unit(mlp_w2, m2_wb, u - 288);
        else if (u < 504) conv_unit(n1_w1,  n1w1b, u - 432);
        else if (u < 576) conv_unit(n1_w2,  n1w2b, u - 504);
        else if (u < 648) conv_unit(n2_w1,  n2w1b, u - 576);
        else if (u < 720) conv_unit(n2_w2,  n2w2b, u - 648);
        else if (u < 912) stats_unit(smf, x, sums1, sumsq1, u - 720);
        else { if (t < 192) { sums2[t] = 0.f; sumsq2[t] = 0.f; } }
    }
    grid_sync(bar, 0);

    // ---- phase B: convx1 ----
    if (bid < 256)
        convx_body(smf, x, sums1, sumsq1, scale1, n1w1b, n1_b1, n1w2b, n1_b2, xb, bid * 16);
    grid_sync(bar, 1);

    // ---- phase C: qkv GEMM (576 tiles) ----
    for (int tile = bid; tile < 576; tile += NB)
        gemm_tile<192, 0>(al, bl, tile & 63, tile >> 6, qkv_wb, qkv_b, xb,
                          (void*)q_buf, nullptr, 576, kv_buf, nullptr, nullptr);
    grid_sync(bar, 2);

    // ---- phase D: attention (XCD-local mapping: block b -> XCD b%8 slab) ----
    {
        int base = (bid & 7) * 384 + (bid >> 3) * 6;
        for (int i = 0; i < 6; i++)
            attn_unit(q_buf, kv_buf, o_attn, base + i);
    }
    grid_sync(bar, 3);

    // ---- phase E: proj GEMM + residual + fused stats atomics (192 tiles) ----
    if (bid < 192)
        gemm_tile<192, 4>(al, bl, bid & 63, bid >> 6, proj_wb, proj_b, o_attn,
                          (void*)x2, x, 192, nullptr, sums2, sumsq2);
    grid_sync(bar, 4);

    // ---- phase F: convx2 ----
    if (bid < 256)
        convx_body(smf, x2, sums2, sumsq2, scale2, n2w1b, n2_b1, n2w2b, n2_b2, xb, bid * 16);
    grid_sync(bar, 5);

    // ---- phase G: mlp1 GEMM (768 tiles, gelu -> m_buf bf16^T) ----
    for (int tile = bid; tile < 768; tile += NB)
        gemm_tile<192, 3>(al, bl, tile & 63, tile >> 6, m1_wb, mlp_b1, xb,
                          (void*)m_buf, nullptr, 768, nullptr, nullptr, nullptr);
    grid_sync(bar, 6);

    // ---- phase H: mlp2 GEMM + residual (in-place x2) ----
    if (bid < 192)
        gemm_tile<768, 2>(al, bl, bid & 63, bid >> 6, m2_wb, mlp_b2, m_buf,
                          (void*)x2, x2, 192, nullptr, nullptr, nullptr);
}

// ---------------------------------------------------------------------------
extern "C" void kernel_launch(void* const* d_in, const int* in_sizes, int n_in,
                              void* d_out, int out_size, void* d_ws, size_t ws_size,
                              hipStream_t stream)
{
    const float* x      = (const float*)d_in[0];
    const float* scale1 = (const float*)d_in[1];
    const float* n1_w1  = (const float*)d_in[2];
    const float* n1_b1  = (const float*)d_in[3];
    const float* n1_w2  = (const float*)d_in[4];
    const float* n1_b2  = (const float*)d_in[5];
    const float* qkv_w  = (const float*)d_in[6];
    const float* qkv_b  = (const float*)d_in[7];
    const float* proj_w = (const float*)d_in[8];
    const float* proj_b = (const float*)d_in[9];
    const float* scale2 = (const float*)d_in[10];
    const float* n2_w1  = (const float*)d_in[11];
    const float* n2_b1  = (const float*)d_in[12];
    const float* n2_w2  = (const float*)d_in[13];
    const float* n2_b2  = (const float*)d_in[14];
    const float* mlp_w1 = (const float*)d_in[15];
    const float* mlp_b1 = (const float*)d_in[16];
    const float* mlp_w2 = (const float*)d_in[17];
    const float* mlp_b2 = (const float*)d_in[18];

    float* ws = (float*)d_ws;
    float* x2 = (float*)d_out;

    // zero the 16 barrier counters (re-executed on every graph replay)
    hipMemsetAsync(ws + 3515136, 0, 64, stream);

    fused<<<NB, 256, 0, stream>>>(x, scale1, n1_w1, n1_b1, n1_w2, n1_b2,
                                  qkv_w, qkv_b, proj_w, proj_b,
                                  scale2, n2_w1, n2_b1, n2_w2, n2_b2,
                                  mlp_w1, mlp_b1, mlp_w2, mlp_b2,
                                  ws, x2);
}

// Round 5
// 312.961 us; speedup vs baseline: 2.5591x; 1.4509x over previous
//
#include <hip/hip_runtime.h>
#include <hip/hip_bf16.h>
#include <cmath>

// Single persistent fused kernel (512 blocks x 256 thr) + 1 tiny memset.
// BARRIER FIX vs R4: hierarchical 2-level barrier. R4's single counter line
// was polled by 512 threads at device scope -> fabric queue on one cacheline
// (~48us/barrier). Now: per-group arrive counters (8 lines x 64 blocks),
// leaders (last arriver per group) meet on a master counter (8 pollers),
// then release a per-group go flag (63 read-only pollers per line, 8 lines).
//  A: weight fp32->bf16 (incl. norm-MLP weights) + stats(x) + zero stats2
//  B: convx1   C: qkv GEMM   D: attention   E: proj GEMM + resid + stats atomics
//  F: convx2   G: mlp1 GEMM  H: mlp2 GEMM + resid
// Residency: LDS 50KB -> 3 blocks/CU (LDS), 8 (waves) -> >=3/CU; 512 <= 768. No deadlock.

#define NPOS 4096
#define C_CH 192
#define NB   512

typedef __bf16 bf16x8 __attribute__((ext_vector_type(8)));
typedef __bf16 bf16x4 __attribute__((ext_vector_type(4)));
typedef float  f32x4  __attribute__((ext_vector_type(4)));

__device__ __forceinline__ float bflo(unsigned int u) {
    union { unsigned int i; float f; } c; c.i = u << 16; return c.f;
}
__device__ __forceinline__ float bfhi(unsigned int u) {
    union { unsigned int i; float f; } c; c.i = u & 0xffff0000u; return c.f;
}

// Hierarchical grid barrier. bar layout per barrier idx (512 uints = 2KB):
//   [grp*16]        : arrive counter for group grp (8 groups x 64 blocks)
//   [128]           : master counter (leaders)
//   [(9+grp)*16]    : go flag for group grp
__device__ __forceinline__ void grid_sync(unsigned* bar, int idx, int bid) {
    __syncthreads();
    if (threadIdx.x == 0) {
        unsigned* base   = bar + idx * 512;
        int grp          = bid & 7;
        unsigned* arr    = base + grp * 16;
        unsigned* master = base + 128;
        unsigned* go     = base + (9 + grp) * 16;
        // arrive (ACQ_REL: release this block's phase writes, join RMW chain)
        unsigned prev = __hip_atomic_fetch_add(arr, 1u, __ATOMIC_ACQ_REL,
                                               __HIP_MEMORY_SCOPE_AGENT);
        if (prev == 63) {   // group leader (last arriver of this group)
            __hip_atomic_fetch_add(master, 1u, __ATOMIC_ACQ_REL,
                                   __HIP_MEMORY_SCOPE_AGENT);
            while (__hip_atomic_load(master, __ATOMIC_RELAXED,
                                     __HIP_MEMORY_SCOPE_AGENT) < 8u)
                __builtin_amdgcn_s_sleep(4);
            (void)__hip_atomic_load(master, __ATOMIC_ACQUIRE,
                                    __HIP_MEMORY_SCOPE_AGENT);
            __hip_atomic_store(go, 1u, __ATOMIC_RELEASE, __HIP_MEMORY_SCOPE_AGENT);
        }
        // all blocks (incl. leader, trivially) poll their group's go flag
        while (__hip_atomic_load(go, __ATOMIC_RELAXED,
                                 __HIP_MEMORY_SCOPE_AGENT) == 0u)
            __builtin_amdgcn_s_sleep(4);
        (void)__hip_atomic_load(go, __ATOMIC_ACQUIRE, __HIP_MEMORY_SCOPE_AGENT);
    }
    __syncthreads();
}

// fp32 -> bf16, 1024 floats per unit (256 thr x float4)
__device__ __forceinline__ void conv_unit(const float* __restrict__ src,
                                          __bf16* __restrict__ dst, int base)
{
    int i = (base * 256 + (int)threadIdx.x) * 4;
    float4 v = *(const float4*)(src + i);
    bf16x4 o = { (__bf16)v.x, (__bf16)v.y, (__bf16)v.z, (__bf16)v.w };
    *(bf16x4*)(dst + i) = o;
}

// per-channel sum / sumsq of one channel (whole block)
__device__ void stats_unit(float* sm, const float* __restrict__ x,
                           float* __restrict__ sums, float* __restrict__ sumsq, int c)
{
    const float4* xc = (const float4*)(x + (size_t)c * NPOS);
    float a = 0.f, a2 = 0.f;
    for (int i = threadIdx.x; i < NPOS / 4; i += 256) {
        float4 v = xc[i];
        a  += v.x + v.y + v.z + v.w;
        a2 += v.x * v.x + v.y * v.y + v.z * v.z + v.w * v.w;
    }
    #pragma unroll
    for (int off = 32; off > 0; off >>= 1) {
        a  += __shfl_down(a, off);
        a2 += __shfl_down(a2, off);
    }
    float* ls = sm; float* ls2 = sm + 4;
    int wid = threadIdx.x >> 6;
    if ((threadIdx.x & 63) == 0) { ls[wid] = a; ls2[wid] = a2; }
    __syncthreads();
    if (threadIdx.x == 0) {
        float t = 0.f, t2 = 0.f;
        #pragma unroll
        for (int w = 0; w < 4; w++) { t += ls[w]; t2 += ls2[w]; }
        sums[c] = t; sumsq[c] = t2;
    }
    __syncthreads();   // sm reused by next unit iteration
}

// gamma-MLP (bf16 weights) + normalize + transpose 16 positions -> xb
__device__ void convx_body(float* sm, const float* __restrict__ x,
    const float* __restrict__ sums, const float* __restrict__ sumsq,
    const float* __restrict__ scale,
    const __bf16* __restrict__ w1b, const float* __restrict__ b1,
    const __bf16* __restrict__ w2b, const float* __restrict__ b2,
    __bf16* __restrict__ xb, int p0)
{
    float* stats = sm;           // 192
    float* h     = sm + 192;     // 384
    float* gsl   = sm + 576;     // 192
    float* lds   = sm + 768;     // 192*17
    int t = threadIdx.x;

    if (t < C_CH) stats[t] = sums[t] * (1.0f / (float)NPOS);
    __syncthreads();
    for (int j = t; j < 384; j += 256) {
        float acc = b1[j];
        const __bf16* wr = w1b + (size_t)j * C_CH;
        #pragma unroll 4
        for (int c = 0; c < C_CH; c += 8) {
            bf16x8 w8 = *(const bf16x8*)(wr + c);
            acc += (float)w8[0] * stats[c]     + (float)w8[1] * stats[c + 1]
                 + (float)w8[2] * stats[c + 2] + (float)w8[3] * stats[c + 3]
                 + (float)w8[4] * stats[c + 4] + (float)w8[5] * stats[c + 5]
                 + (float)w8[6] * stats[c + 6] + (float)w8[7] * stats[c + 7];
        }
        h[j] = fmaxf(acc, 0.0f);
    }
    __syncthreads();
    if (t < C_CH) {
        float acc = b2[t];
        const __bf16* wr = w2b + (size_t)t * 384;
        #pragma unroll 4
        for (int j = 0; j < 384; j += 8) {
            bf16x8 w8 = *(const bf16x8*)(wr + j);
            acc += (float)w8[0] * h[j]     + (float)w8[1] * h[j + 1]
                 + (float)w8[2] * h[j + 2] + (float)w8[3] * h[j + 3]
                 + (float)w8[4] * h[j + 4] + (float)w8[5] * h[j + 5]
                 + (float)w8[6] * h[j + 6] + (float)w8[7] * h[j + 7];
        }
        float g = 1.0f / (1.0f + __expf(-acc));
        float rms = sqrtf(sumsq[t] * (1.0f / (float)NPOS) + 1e-6f);
        gsl[t] = scale[t] * g / rms;
    }
    __syncthreads();
    for (int idx = t; idx < 192 * 4; idx += 256) {
        int row = idx >> 2, p4 = idx & 3;
        float4 v = *(const float4*)(x + (size_t)row * NPOS + p0 + p4 * 4);
        float g = gsl[row];
        lds[row * 17 + p4 * 4 + 0] = v.x * g;
        lds[row * 17 + p4 * 4 + 1] = v.y * g;
        lds[row * 17 + p4 * 4 + 2] = v.z * g;
        lds[row * 17 + p4 * 4 + 3] = v.w * g;
    }
    __syncthreads();
    for (int idx = t; idx < 48 * 16; idx += 256) {
        int c4 = idx >> 4, p = idx & 15;
        bf16x4 o;
        #pragma unroll
        for (int j = 0; j < 4; j++) o[j] = (__bf16)lds[(c4 * 4 + j) * 17 + p];
        *(bf16x4*)(xb + (size_t)(p0 + p) * 192 + c4 * 4) = o;
    }
    __syncthreads();
}

// one 64x64 MFMA GEMM tile; EPI: 0=qkv scatter, 2=resid add, 3=gelu bf16^T,
// 4=resid add + fused per-channel sum/sumsq atomics
template <int K, int EPI>
__device__ void gemm_tile(__bf16* al, __bf16* bl, int bx, int by,
    const __bf16* __restrict__ W, const float* __restrict__ bias,
    const __bf16* __restrict__ X, void* __restrict__ out,
    const float* __restrict__ resid, int M, __bf16* __restrict__ out_kv,
    float* __restrict__ s2sum, float* __restrict__ s2sq)
{
    constexpr int KC  = 192;
    constexpr int LDA = 200;
    int t    = threadIdx.x;
    int lane = t & 63;
    int wv   = t >> 6;
    int r16  = lane & 15;
    int quad = lane >> 4;
    int wvm  = wv >> 1;
    int wvn  = wv & 1;
    int mBase = by * 64;
    int nBase = bx * 64;

    f32x4 acc[2][2];
    #pragma unroll
    for (int i = 0; i < 2; i++)
        #pragma unroll
        for (int j = 0; j < 2; j++)
            acc[i][j] = (f32x4){0.f, 0.f, 0.f, 0.f};

    for (int k0 = 0; k0 < K; k0 += KC) {
        #pragma unroll
        for (int it = 0; it < 6; it++) {
            int c = it * 256 + t;
            int row = c / 24, off = c - row * 24;
            bf16x8 va = *(const bf16x8*)(W + (size_t)(mBase + row) * K + k0 + off * 8);
            *(bf16x8*)(al + row * LDA + off * 8) = va;
            bf16x8 vb = *(const bf16x8*)(X + (size_t)(nBase + row) * K + k0 + off * 8);
            *(bf16x8*)(bl + row * LDA + off * 8) = vb;
        }
        __syncthreads();
        #pragma unroll
        for (int ks = 0; ks < KC / 32; ks++) {
            bf16x8 a0 = *(const bf16x8*)(al + (wvm * 32 + r16) * LDA + ks * 32 + quad * 8);
            bf16x8 a1 = *(const bf16x8*)(al + (wvm * 32 + 16 + r16) * LDA + ks * 32 + quad * 8);
            bf16x8 b0 = *(const bf16x8*)(bl + (wvn * 32 + r16) * LDA + ks * 32 + quad * 8);
            bf16x8 b1 = *(const bf16x8*)(bl + (wvn * 32 + 16 + r16) * LDA + ks * 32 + quad * 8);
            acc[0][0] = __builtin_amdgcn_mfma_f32_16x16x32_bf16(a0, b0, acc[0][0], 0, 0, 0);
            acc[0][1] = __builtin_amdgcn_mfma_f32_16x16x32_bf16(a0, b1, acc[0][1], 0, 0, 0);
            acc[1][0] = __builtin_amdgcn_mfma_f32_16x16x32_bf16(a1, b0, acc[1][0], 0, 0, 0);
            acc[1][1] = __builtin_amdgcn_mfma_f32_16x16x32_bf16(a1, b1, acc[1][1], 0, 0, 0);
        }
        __syncthreads();
    }

    #pragma unroll
    for (int rt = 0; rt < 2; rt++) {
        int m0 = mBase + wvm * 32 + rt * 16 + quad * 4;
        float b0 = bias[m0], b1v = bias[m0 + 1], b2v = bias[m0 + 2], b3v = bias[m0 + 3];
        float ss[4] = {0.f, 0.f, 0.f, 0.f}, sq[4] = {0.f, 0.f, 0.f, 0.f};
        #pragma unroll
        for (int ct = 0; ct < 2; ct++) {
            int n = nBase + wvn * 32 + ct * 16 + r16;
            f32x4 a4 = acc[rt][ct];
            float g0 = a4[0] + b0, g1 = a4[1] + b1v, g2 = a4[2] + b2v, g3 = a4[3] + b3v;
            if (EPI == 0) {
                int sect = m0 / 192;
                int o0 = m0 - sect * 192;
                if (sect == 0) {
                    const float qs = 0.17677669529663687f;   // 32^-0.5 folded into q
                    *(float4*)((float*)out + (size_t)n * 192 + o0) =
                        make_float4(g0 * qs, g1 * qs, g2 * qs, g3 * qs);
                } else {
                    bf16x4 kvv = { (__bf16)g0, (__bf16)g1, (__bf16)g2, (__bf16)g3 };
                    *(bf16x4*)(out_kv + (size_t)n * 384 + (o0 >> 2) * 8 + (sect - 1) * 4) = kvv;
                }
            } else if (EPI == 2 || EPI == 4) {
                float* o = (float*)out;
                size_t i0 = (size_t)m0 * NPOS + n;
                float v0 = g0 + resid[i0];
                float v1 = g1 + resid[i0 + NPOS];
                float v2 = g2 + resid[i0 + 2 * NPOS];
                float v3 = g3 + resid[i0 + 3 * NPOS];
                o[i0] = v0; o[i0 + NPOS] = v1; o[i0 + 2 * NPOS] = v2; o[i0 + 3 * NPOS] = v3;
                if (EPI == 4) {
                    ss[0] += v0; sq[0] += v0 * v0;
                    ss[1] += v1; sq[1] += v1 * v1;
                    ss[2] += v2; sq[2] += v2 * v2;
                    ss[3] += v3; sq[3] += v3 * v3;
                }
            } else {
                bf16x4 v;
                v[0] = (__bf16)(0.5f * g0 * (1.0f + erff(g0 * 0.7071067811865475f)));
                v[1] = (__bf16)(0.5f * g1 * (1.0f + erff(g1 * 0.7071067811865475f)));
                v[2] = (__bf16)(0.5f * g2 * (1.0f + erff(g2 * 0.7071067811865475f)));
                v[3] = (__bf16)(0.5f * g3 * (1.0f + erff(g3 * 0.7071067811865475f)));
                *(bf16x4*)((__bf16*)out + (size_t)n * M + m0) = v;
            }
        }
        if (EPI == 4) {
            #pragma unroll
            for (int j = 0; j < 4; j++) {
                float s = ss[j], s2v = sq[j];
                #pragma unroll
                for (int off = 8; off >= 1; off >>= 1) {
                    s   += __shfl_down(s, off);
                    s2v += __shfl_down(s2v, off);
                }
                if (r16 == 0) {
                    atomicAdd(&s2sum[m0 + j], s);
                    atomicAdd(&s2sq[m0 + j], s2v);
                }
            }
        }
    }
}

// one attention unit = 8 (pos,head) pairs over the block's 256 threads
__device__ __forceinline__ void attn_unit(const float* __restrict__ q,
    const __bf16* __restrict__ kv, __bf16* __restrict__ o, int unit)
{
    int t = threadIdx.x;
    int pairIdx = unit * 8 + (t >> 5);
    int sg   = (t >> 3) & 3;
    int lane = t & 7;
    int pos = pairIdx / 6;
    int head = pairIdx - pos * 6;
    int wq = pos & 15;
    int hq = (pos >> 4) & 15;
    int dq = pos >> 8;
    int d0 = min(max(dq - 2, 0), 11);
    int h0 = min(max(hq - 2, 0), 11);
    int w0 = min(max(wq - 2, 0), 11);

    const __bf16* kvb = kv + head * 64 + lane * 8;
    float4 q4 = *(const float4*)(q + (size_t)pos * 192 + head * 32 + lane * 4);

    float l = 0.0f;
    float4 acc = make_float4(0.f, 0.f, 0.f, 0.f);

    for (int dh = sg; dh < 25; dh += 4) {
        int di = dh / 5;
        int hi = dh - di * 5;
        int np0 = (d0 + di) * 256 + (h0 + hi) * 16 + w0;
        const __bf16* p = kvb + (size_t)np0 * 384;
        #pragma unroll
        for (int wi = 0; wi < 5; wi++) {
            uint4 u = *(const uint4*)p;
            float s = q4.x * bflo(u.x) + q4.y * bfhi(u.x)
                    + q4.z * bflo(u.y) + q4.w * bfhi(u.y);
            s += __shfl_xor(s, 1);
            s += __shfl_xor(s, 2);
            s += __shfl_xor(s, 4);
            float pr = __expf(s);
            l += pr;
            acc.x += pr * bflo(u.z);
            acc.y += pr * bfhi(u.z);
            acc.z += pr * bflo(u.w);
            acc.w += pr * bfhi(u.w);
            p += 384;
        }
    }

    #pragma unroll
    for (int off = 8; off <= 16; off <<= 1) {
        l     += __shfl_xor(l, off);
        acc.x += __shfl_xor(acc.x, off);
        acc.y += __shfl_xor(acc.y, off);
        acc.z += __shfl_xor(acc.z, off);
        acc.w += __shfl_xor(acc.w, off);
    }

    if (sg == 0) {
        float rl = 1.0f / l;
        bf16x4 ov = { (__bf16)(acc.x * rl), (__bf16)(acc.y * rl),
                      (__bf16)(acc.z * rl), (__bf16)(acc.w * rl) };
        *(bf16x4*)(o + (size_t)pos * 192 + head * 32 + lane * 4) = ov;
    }
}

__global__ __launch_bounds__(256) void fused(
    const float* __restrict__ x, const float* __restrict__ scale1,
    const float* __restrict__ n1_w1, const float* __restrict__ n1_b1,
    const float* __restrict__ n1_w2, const float* __restrict__ n1_b2,
    const float* __restrict__ qkv_w, const float* __restrict__ qkv_b,
    const float* __restrict__ proj_w, const float* __restrict__ proj_b,
    const float* __restrict__ scale2,
    const float* __restrict__ n2_w1, const float* __restrict__ n2_b1,
    const float* __restrict__ n2_w2, const float* __restrict__ n2_b2,
    const float* __restrict__ mlp_w1, const float* __restrict__ mlp_b1,
    const float* __restrict__ mlp_w2, const float* __restrict__ mlp_b2,
    float* __restrict__ ws, float* __restrict__ x2)
{
    __shared__ __align__(16) char smraw[51200];   // GEMM al|bl; convx/stats reuse
    __bf16* al  = (__bf16*)smraw;
    __bf16* bl  = al + 64 * 200;
    float*  smf = (float*)smraw;

    float*  q_buf   = ws;
    __bf16* kv_buf  = (__bf16*)(ws + 786432);
    __bf16* m_buf   = (__bf16*)ws;                 // aliases q+kv (dead after attn)
    __bf16* xb      = (__bf16*)(ws + 2359296);
    __bf16* o_attn  = (__bf16*)(ws + 2752512);
    __bf16* qkv_wb  = (__bf16*)(ws + 3145728);
    __bf16* proj_wb = qkv_wb + 110592;
    __bf16* m1_wb   = proj_wb + 36864;
    __bf16* m2_wb   = m1_wb + 147456;
    float*  sums1   = ws + 3366912;
    float*  sumsq1  = ws + 3367104;
    float*  sums2   = ws + 3367296;
    float*  sumsq2  = ws + 3367488;
    __bf16* n1w1b   = (__bf16*)(ws + 3367680);
    __bf16* n1w2b   = n1w1b + 73728;
    __bf16* n2w1b   = n1w2b + 73728;
    __bf16* n2w2b   = n2w1b + 73728;
    unsigned* bar   = (unsigned*)(ws + 3515136);

    int bid = blockIdx.x;
    int t   = threadIdx.x;

    // ---- phase A: weight conversions + stats(x) + zero stats2 ----
    for (int u = bid; u < 913; u += NB) {
        if      (u < 108) conv_unit(qkv_w,  qkv_wb, u);
        else if (u < 144) conv_unit(proj_w, proj_wb, u - 108);
        else if (u < 288) conv_unit(mlp_w1, m1_wb, u - 144);
        else if (u < 432) conv_unit(mlp_w2, m2_wb, u - 288);
        else if (u < 504) conv_unit(n1_w1,  n1w1b, u - 432);
        else if (u < 576) conv_unit(n1_w2,  n1w2b, u - 504);
        else if (u < 648) conv_unit(n2_w1,  n2w1b, u - 576);
        else if (u < 720) conv_unit(n2_w2,  n2w2b, u - 648);
        else if (u < 912) stats_unit(smf, x, sums1, sumsq1, u - 720);
        else { if (t < 192) { sums2[t] = 0.f; sumsq2[t] = 0.f; } }
    }
    grid_sync(bar, 0, bid);

    // ---- phase B: convx1 ----
    if (bid < 256)
        convx_body(smf, x, sums1, sumsq1, scale1, n1w1b, n1_b1, n1w2b, n1_b2, xb, bid * 16);
    grid_sync(bar, 1, bid);

    // ---- phase C: qkv GEMM (576 tiles) ----
    for (int tile = bid; tile < 576; tile += NB)
        gemm_tile<192, 0>(al, bl, tile & 63, tile >> 6, qkv_wb, qkv_b, xb,
                          (void*)q_buf, nullptr, 576, kv_buf, nullptr, nullptr);
    grid_sync(bar, 2, bid);

    // ---- phase D: attention (XCD-local mapping: block b -> slab b%8) ----
    {
        int base = (bid & 7) * 384 + (bid >> 3) * 6;
        for (int i = 0; i < 6; i++)
            attn_unit(q_buf, kv_buf, o_attn, base + i);
    }
    grid_sync(bar, 3, bid);

    // ---- phase E: proj GEMM + residual + fused stats atomics (192 tiles) ----
    if (bid < 192)
        gemm_tile<192, 4>(al, bl, bid & 63, bid >> 6, proj_wb, proj_b, o_attn,
                          (void*)x2, x, 192, nullptr, sums2, sumsq2);
    grid_sync(bar, 4, bid);

    // ---- phase F: convx2 ----
    if (bid < 256)
        convx_body(smf, x2, sums2, sumsq2, scale2, n2w1b, n2_b1, n2w2b, n2_b2, xb, bid * 16);
    grid_sync(bar, 5, bid);

    // ---- phase G: mlp1 GEMM (768 tiles, gelu -> m_buf bf16^T) ----
    for (int tile = bid; tile < 768; tile += NB)
        gemm_tile<192, 3>(al, bl, tile & 63, tile >> 6, m1_wb, mlp_b1, xb,
                          (void*)m_buf, nullptr, 768, nullptr, nullptr, nullptr);
    grid_sync(bar, 6, bid);

    // ---- phase H: mlp2 GEMM + residual (in-place x2) ----
    if (bid < 192)
        gemm_tile<768, 2>(al, bl, bid & 63, bid >> 6, m2_wb, mlp_b2, m_buf,
                          (void*)x2, x2, 192, nullptr, nullptr, nullptr);
}

// ---------------------------------------------------------------------------
extern "C" void kernel_launch(void* const* d_in, const int* in_sizes, int n_in,
                              void* d_out, int out_size, void* d_ws, size_t ws_size,
                              hipStream_t stream)
{
    const float* x      = (const float*)d_in[0];
    const float* scale1 = (const float*)d_in[1];
    const float* n1_w1  = (const float*)d_in[2];
    const float* n1_b1  = (const float*)d_in[3];
    const float* n1_w2  = (const float*)d_in[4];
    const float* n1_b2  = (const float*)d_in[5];
    const float* qkv_w  = (const float*)d_in[6];
    const float* qkv_b  = (const float*)d_in[7];
    const float* proj_w = (const float*)d_in[8];
    const float* proj_b = (const float*)d_in[9];
    const float* scale2 = (const float*)d_in[10];
    const float* n2_w1  = (const float*)d_in[11];
    const float* n2_b1  = (const float*)d_in[12];
    const float* n2_w2  = (const float*)d_in[13];
    const float* n2_b2  = (const float*)d_in[14];
    const float* mlp_w1 = (const float*)d_in[15];
    const float* mlp_b1 = (const float*)d_in[16];
    const float* mlp_w2 = (const float*)d_in[17];
    const float* mlp_b2 = (const float*)d_in[18];

    float* ws = (float*)d_ws;
    float* x2 = (float*)d_out;

    // zero the barrier state: 7 barriers x 512 uints = 14KB (re-zeroed per replay)
    hipMemsetAsync(ws + 3515136, 0, 7 * 512 * sizeof(unsigned), stream);

    fused<<<NB, 256, 0, stream>>>(x, scale1, n1_w1, n1_b1, n1_w2, n1_b2,
                                  qkv_w, qkv_b, proj_w, proj_b,
                                  scale2, n2_w1, n2_b1, n2_w2, n2_b2,
                                  mlp_w1, mlp_b1, mlp_w2, mlp_b2,
                                  ws, x2);
}

// Round 6
// 202.036 us; speedup vs baseline: 3.9641x; 1.5490x over previous
//
#include <hip/hip_runtime.h>
#include <hip/hip_bf16.h>
#include <cmath>

// Single persistent fused kernel (512 blocks x 256 thr) + 1 tiny memset.
// BARRIER FIX vs R5: per-XCD cache maintenance. R5 did 512 ACQ_REL arrivals
// (each = buffer_wbl2 + buffer_inv) + 512 acquire loads (buffer_inv) per
// barrier -> ~1500 whole-L2 maintenance ops, ~24us/barrier. Now: blocks
// arrive RELAXED on a counter keyed by REAL XCD (s_getreg HW_REG_XCC_ID);
// the last arriver per XCD does ONE RELEASE RMW on the master (= one
// buffer_wbl2 for that XCD), leaders poll master==nXCD, set per-XCD go flag.
// NO acquire-inv anywhere: every cross-phase buffer is first-touch-written
// (m_buf un-aliased, xb2 added for the convx2->mlp1 path) so no stale clean
// L2 copies can exist; stats sums flow through coherent-point atomics.
//  A: weight fp32->bf16 + stats(x) + zero stats2   B: convx1
//  C: qkv GEMM   D: attention   E: proj GEMM + resid + stats atomics
//  F: convx2 (->xb2)   G: mlp1 GEMM (->m_buf)   H: mlp2 GEMM + resid
// Residency: LDS 50KB -> 3 blocks/CU; 512 <= 768. No deadlock.

#define NPOS 4096
#define C_CH 192
#define NB   512

typedef __bf16 bf16x8 __attribute__((ext_vector_type(8)));
typedef __bf16 bf16x4 __attribute__((ext_vector_type(4)));
typedef float  f32x4  __attribute__((ext_vector_type(4)));

__device__ __forceinline__ float bflo(unsigned int u) {
    union { unsigned int i; float f; } c; c.i = u << 16; return c.f;
}
__device__ __forceinline__ float bfhi(unsigned int u) {
    union { unsigned int i; float f; } c; c.i = u & 0xffff0000u; return c.f;
}

// bar layout (uints): pop[x]=bar[x*16]; preArr[g]=bar[128+g*16];
// preMaster=bar[256]; preGo[g]=bar[272+g*16];
// data barrier i: base=512+i*512: arr[x]=base+x*16, master=base+128,
// go[x]=base+144+x*16.  Total 4096 uints = 16KB, memset per launch.

// startup barrier: no data deps -> pure relaxed atomics, zero cache ops
__device__ __forceinline__ void pre_sync(unsigned* bar, int grp) {
    __syncthreads();
    if (threadIdx.x == 0) {
        unsigned* arr    = bar + 128 + grp * 16;
        unsigned* master = bar + 256;
        unsigned* go     = bar + 272 + grp * 16;
        unsigned prev = __hip_atomic_fetch_add(arr, 1u, __ATOMIC_RELAXED,
                                               __HIP_MEMORY_SCOPE_AGENT);
        if (prev == 63u) {   // groups of exactly 64 by bid&7 construction
            __hip_atomic_fetch_add(master, 1u, __ATOMIC_RELAXED,
                                   __HIP_MEMORY_SCOPE_AGENT);
            while (__hip_atomic_load(master, __ATOMIC_RELAXED,
                                     __HIP_MEMORY_SCOPE_AGENT) < 8u)
                __builtin_amdgcn_s_sleep(2);
            __hip_atomic_store(go, 1u, __ATOMIC_RELAXED, __HIP_MEMORY_SCOPE_AGENT);
        }
        while (__hip_atomic_load(go, __ATOMIC_RELAXED,
                                 __HIP_MEMORY_SCOPE_AGENT) == 0u)
            __builtin_amdgcn_s_sleep(2);
    }
    __syncthreads();
}

// data barrier: relaxed arrive per block; last arriver per REAL XCD does one
// RELEASE RMW (= one buffer_wbl2 flushing this XCD's dirty phase output).
// __syncthreads has already drained vmcnt, so all the XCD's stores are in L2.
__device__ __forceinline__ void grid_sync(unsigned* bar, int idx, int xcc,
                                          unsigned myPop, unsigned nx) {
    __syncthreads();
    if (threadIdx.x == 0) {
        unsigned* base   = bar + 512 + idx * 512;
        unsigned* arr    = base + xcc * 16;
        unsigned* master = base + 128;
        unsigned* go     = base + 144 + xcc * 16;
        unsigned prev = __hip_atomic_fetch_add(arr, 1u, __ATOMIC_RELAXED,
                                               __HIP_MEMORY_SCOPE_AGENT);
        if (prev == myPop - 1u) {   // last block on this XCD
            __hip_atomic_fetch_add(master, 1u, __ATOMIC_RELEASE,   // wbl2 here
                                   __HIP_MEMORY_SCOPE_AGENT);
            while (__hip_atomic_load(master, __ATOMIC_RELAXED,
                                     __HIP_MEMORY_SCOPE_AGENT) < nx)
                __builtin_amdgcn_s_sleep(2);
            __hip_atomic_store(go, 1u, __ATOMIC_RELAXED, __HIP_MEMORY_SCOPE_AGENT);
        }
        while (__hip_atomic_load(go, __ATOMIC_RELAXED,
                                 __HIP_MEMORY_SCOPE_AGENT) == 0u)
            __builtin_amdgcn_s_sleep(2);
    }
    __syncthreads();
}

// fp32 -> bf16, 1024 floats per unit (256 thr x float4)
__device__ __forceinline__ void conv_unit(const float* __restrict__ src,
                                          __bf16* __restrict__ dst, int base)
{
    int i = (base * 256 + (int)threadIdx.x) * 4;
    float4 v = *(const float4*)(src + i);
    bf16x4 o = { (__bf16)v.x, (__bf16)v.y, (__bf16)v.z, (__bf16)v.w };
    *(bf16x4*)(dst + i) = o;
}

// per-channel sum / sumsq of one channel (whole block)
__device__ void stats_unit(float* sm, const float* __restrict__ x,
                           float* __restrict__ sums, float* __restrict__ sumsq, int c)
{
    const float4* xc = (const float4*)(x + (size_t)c * NPOS);
    float a = 0.f, a2 = 0.f;
    for (int i = threadIdx.x; i < NPOS / 4; i += 256) {
        float4 v = xc[i];
        a  += v.x + v.y + v.z + v.w;
        a2 += v.x * v.x + v.y * v.y + v.z * v.z + v.w * v.w;
    }
    #pragma unroll
    for (int off = 32; off > 0; off >>= 1) {
        a  += __shfl_down(a, off);
        a2 += __shfl_down(a2, off);
    }
    float* ls = sm; float* ls2 = sm + 4;
    int wid = threadIdx.x >> 6;
    if ((threadIdx.x & 63) == 0) { ls[wid] = a; ls2[wid] = a2; }
    __syncthreads();
    if (threadIdx.x == 0) {
        float t = 0.f, t2 = 0.f;
        #pragma unroll
        for (int w = 0; w < 4; w++) { t += ls[w]; t2 += ls2[w]; }
        sums[c] = t; sumsq[c] = t2;
    }
    __syncthreads();   // sm reused by next unit iteration
}

// gamma-MLP (bf16 weights) + normalize + transpose 16 positions -> xb.
// sums/sumsq read via coherent-point atomics (E accumulates them there).
__device__ void convx_body(float* sm, const float* __restrict__ x,
    const float* __restrict__ sums, const float* __restrict__ sumsq,
    const float* __restrict__ scale,
    const __bf16* __restrict__ w1b, const float* __restrict__ b1,
    const __bf16* __restrict__ w2b, const float* __restrict__ b2,
    __bf16* __restrict__ xb, int p0)
{
    float* stats = sm;           // 192
    float* h     = sm + 192;     // 384
    float* gsl   = sm + 576;     // 192
    float* lds   = sm + 768;     // 192*17
    int t = threadIdx.x;

    if (t < C_CH)
        stats[t] = __hip_atomic_load((const float*)&sums[t], __ATOMIC_RELAXED,
                                     __HIP_MEMORY_SCOPE_AGENT) * (1.0f / (float)NPOS);
    __syncthreads();
    for (int j = t; j < 384; j += 256) {
        float acc = b1[j];
        const __bf16* wr = w1b + (size_t)j * C_CH;
        #pragma unroll 4
        for (int c = 0; c < C_CH; c += 8) {
            bf16x8 w8 = *(const bf16x8*)(wr + c);
            acc += (float)w8[0] * stats[c]     + (float)w8[1] * stats[c + 1]
                 + (float)w8[2] * stats[c + 2] + (float)w8[3] * stats[c + 3]
                 + (float)w8[4] * stats[c + 4] + (float)w8[5] * stats[c + 5]
                 + (float)w8[6] * stats[c + 6] + (float)w8[7] * stats[c + 7];
        }
        h[j] = fmaxf(acc, 0.0f);
    }
    __syncthreads();
    if (t < C_CH) {
        float acc = b2[t];
        const __bf16* wr = w2b + (size_t)t * 384;
        #pragma unroll 4
        for (int j = 0; j < 384; j += 8) {
            bf16x8 w8 = *(const bf16x8*)(wr + j);
            acc += (float)w8[0] * h[j]     + (float)w8[1] * h[j + 1]
                 + (float)w8[2] * h[j + 2] + (float)w8[3] * h[j + 3]
                 + (float)w8[4] * h[j + 4] + (float)w8[5] * h[j + 5]
                 + (float)w8[6] * h[j + 6] + (float)w8[7] * h[j + 7];
        }
        float g = 1.0f / (1.0f + __expf(-acc));
        float sq = __hip_atomic_load((const float*)&sumsq[t], __ATOMIC_RELAXED,
                                     __HIP_MEMORY_SCOPE_AGENT);
        float rms = sqrtf(sq * (1.0f / (float)NPOS) + 1e-6f);
        gsl[t] = scale[t] * g / rms;
    }
    __syncthreads();
    for (int idx = t; idx < 192 * 4; idx += 256) {
        int row = idx >> 2, p4 = idx & 3;
        float4 v = *(const float4*)(x + (size_t)row * NPOS + p0 + p4 * 4);
        float g = gsl[row];
        lds[row * 17 + p4 * 4 + 0] = v.x * g;
        lds[row * 17 + p4 * 4 + 1] = v.y * g;
        lds[row * 17 + p4 * 4 + 2] = v.z * g;
        lds[row * 17 + p4 * 4 + 3] = v.w * g;
    }
    __syncthreads();
    for (int idx = t; idx < 48 * 16; idx += 256) {
        int c4 = idx >> 4, p = idx & 15;
        bf16x4 o;
        #pragma unroll
        for (int j = 0; j < 4; j++) o[j] = (__bf16)lds[(c4 * 4 + j) * 17 + p];
        *(bf16x4*)(xb + (size_t)(p0 + p) * 192 + c4 * 4) = o;
    }
    __syncthreads();
}

// one 64x64 MFMA GEMM tile; EPI: 0=qkv scatter, 2=resid add, 3=gelu bf16^T,
// 4=resid add + fused per-channel sum/sumsq atomics
template <int K, int EPI>
__device__ void gemm_tile(__bf16* al, __bf16* bl, int bx, int by,
    const __bf16* __restrict__ W, const float* __restrict__ bias,
    const __bf16* __restrict__ X, void* __restrict__ out,
    const float* __restrict__ resid, int M, __bf16* __restrict__ out_kv,
    float* __restrict__ s2sum, float* __restrict__ s2sq)
{
    constexpr int KC  = 192;
    constexpr int LDA = 200;
    int t    = threadIdx.x;
    int lane = t & 63;
    int wv   = t >> 6;
    int r16  = lane & 15;
    int quad = lane >> 4;
    int wvm  = wv >> 1;
    int wvn  = wv & 1;
    int mBase = by * 64;
    int nBase = bx * 64;

    f32x4 acc[2][2];
    #pragma unroll
    for (int i = 0; i < 2; i++)
        #pragma unroll
        for (int j = 0; j < 2; j++)
            acc[i][j] = (f32x4){0.f, 0.f, 0.f, 0.f};

    for (int k0 = 0; k0 < K; k0 += KC) {
        #pragma unroll
        for (int it = 0; it < 6; it++) {
            int c = it * 256 + t;
            int row = c / 24, off = c - row * 24;
            bf16x8 va = *(const bf16x8*)(W + (size_t)(mBase + row) * K + k0 + off * 8);
            *(bf16x8*)(al + row * LDA + off * 8) = va;
            bf16x8 vb = *(const bf16x8*)(X + (size_t)(nBase + row) * K + k0 + off * 8);
            *(bf16x8*)(bl + row * LDA + off * 8) = vb;
        }
        __syncthreads();
        #pragma unroll
        for (int ks = 0; ks < KC / 32; ks++) {
            bf16x8 a0 = *(const bf16x8*)(al + (wvm * 32 + r16) * LDA + ks * 32 + quad * 8);
            bf16x8 a1 = *(const bf16x8*)(al + (wvm * 32 + 16 + r16) * LDA + ks * 32 + quad * 8);
            bf16x8 b0 = *(const bf16x8*)(bl + (wvn * 32 + r16) * LDA + ks * 32 + quad * 8);
            bf16x8 b1 = *(const bf16x8*)(bl + (wvn * 32 + 16 + r16) * LDA + ks * 32 + quad * 8);
            acc[0][0] = __builtin_amdgcn_mfma_f32_16x16x32_bf16(a0, b0, acc[0][0], 0, 0, 0);
            acc[0][1] = __builtin_amdgcn_mfma_f32_16x16x32_bf16(a0, b1, acc[0][1], 0, 0, 0);
            acc[1][0] = __builtin_amdgcn_mfma_f32_16x16x32_bf16(a1, b0, acc[1][0], 0, 0, 0);
            acc[1][1] = __builtin_amdgcn_mfma_f32_16x16x32_bf16(a1, b1, acc[1][1], 0, 0, 0);
        }
        __syncthreads();
    }

    #pragma unroll
    for (int rt = 0; rt < 2; rt++) {
        int m0 = mBase + wvm * 32 + rt * 16 + quad * 4;
        float b0 = bias[m0], b1v = bias[m0 + 1], b2v = bias[m0 + 2], b3v = bias[m0 + 3];
        float ss[4] = {0.f, 0.f, 0.f, 0.f}, sq[4] = {0.f, 0.f, 0.f, 0.f};
        #pragma unroll
        for (int ct = 0; ct < 2; ct++) {
            int n = nBase + wvn * 32 + ct * 16 + r16;
            f32x4 a4 = acc[rt][ct];
            float g0 = a4[0] + b0, g1 = a4[1] + b1v, g2 = a4[2] + b2v, g3 = a4[3] + b3v;
            if (EPI == 0) {
                int sect = m0 / 192;
                int o0 = m0 - sect * 192;
                if (sect == 0) {
                    const float qs = 0.17677669529663687f;   // 32^-0.5 folded into q
                    *(float4*)((float*)out + (size_t)n * 192 + o0) =
                        make_float4(g0 * qs, g1 * qs, g2 * qs, g3 * qs);
                } else {
                    bf16x4 kvv = { (__bf16)g0, (__bf16)g1, (__bf16)g2, (__bf16)g3 };
                    *(bf16x4*)(out_kv + (size_t)n * 384 + (o0 >> 2) * 8 + (sect - 1) * 4) = kvv;
                }
            } else if (EPI == 2 || EPI == 4) {
                float* o = (float*)out;
                size_t i0 = (size_t)m0 * NPOS + n;
                float v0 = g0 + resid[i0];
                float v1 = g1 + resid[i0 + NPOS];
                float v2 = g2 + resid[i0 + 2 * NPOS];
                float v3 = g3 + resid[i0 + 3 * NPOS];
                o[i0] = v0; o[i0 + NPOS] = v1; o[i0 + 2 * NPOS] = v2; o[i0 + 3 * NPOS] = v3;
                if (EPI == 4) {
                    ss[0] += v0; sq[0] += v0 * v0;
                    ss[1] += v1; sq[1] += v1 * v1;
                    ss[2] += v2; sq[2] += v2 * v2;
                    ss[3] += v3; sq[3] += v3 * v3;
                }
            } else {
                bf16x4 v;
                v[0] = (__bf16)(0.5f * g0 * (1.0f + erff(g0 * 0.7071067811865475f)));
                v[1] = (__bf16)(0.5f * g1 * (1.0f + erff(g1 * 0.7071067811865475f)));
                v[2] = (__bf16)(0.5f * g2 * (1.0f + erff(g2 * 0.7071067811865475f)));
                v[3] = (__bf16)(0.5f * g3 * (1.0f + erff(g3 * 0.7071067811865475f)));
                *(bf16x4*)((__bf16*)out + (size_t)n * M + m0) = v;
            }
        }
        if (EPI == 4) {
            #pragma unroll
            for (int j = 0; j < 4; j++) {
                float s = ss[j], s2v = sq[j];
                #pragma unroll
                for (int off = 8; off >= 1; off >>= 1) {
                    s   += __shfl_down(s, off);
                    s2v += __shfl_down(s2v, off);
                }
                if (r16 == 0) {
                    atomicAdd(&s2sum[m0 + j], s);
                    atomicAdd(&s2sq[m0 + j], s2v);
                }
            }
        }
    }
}

// one attention unit = 8 (pos,head) pairs over the block's 256 threads
__device__ __forceinline__ void attn_unit(const float* __restrict__ q,
    const __bf16* __restrict__ kv, __bf16* __restrict__ o, int unit)
{
    int t = threadIdx.x;
    int pairIdx = unit * 8 + (t >> 5);
    int sg   = (t >> 3) & 3;
    int lane = t & 7;
    int pos = pairIdx / 6;
    int head = pairIdx - pos * 6;
    int wq = pos & 15;
    int hq = (pos >> 4) & 15;
    int dq = pos >> 8;
    int d0 = min(max(dq - 2, 0), 11);
    int h0 = min(max(hq - 2, 0), 11);
    int w0 = min(max(wq - 2, 0), 11);

    const __bf16* kvb = kv + head * 64 + lane * 8;
    float4 q4 = *(const float4*)(q + (size_t)pos * 192 + head * 32 + lane * 4);

    float l = 0.0f;
    float4 acc = make_float4(0.f, 0.f, 0.f, 0.f);

    for (int dh = sg; dh < 25; dh += 4) {
        int di = dh / 5;
        int hi = dh - di * 5;
        int np0 = (d0 + di) * 256 + (h0 + hi) * 16 + w0;
        const __bf16* p = kvb + (size_t)np0 * 384;
        #pragma unroll
        for (int wi = 0; wi < 5; wi++) {
            uint4 u = *(const uint4*)p;
            float s = q4.x * bflo(u.x) + q4.y * bfhi(u.x)
                    + q4.z * bflo(u.y) + q4.w * bfhi(u.y);
            s += __shfl_xor(s, 1);
            s += __shfl_xor(s, 2);
            s += __shfl_xor(s, 4);
            float pr = __expf(s);
            l += pr;
            acc.x += pr * bflo(u.z);
            acc.y += pr * bfhi(u.z);
            acc.z += pr * bflo(u.w);
            acc.w += pr * bfhi(u.w);
            p += 384;
        }
    }

    #pragma unroll
    for (int off = 8; off <= 16; off <<= 1) {
        l     += __shfl_xor(l, off);
        acc.x += __shfl_xor(acc.x, off);
        acc.y += __shfl_xor(acc.y, off);
        acc.z += __shfl_xor(acc.z, off);
        acc.w += __shfl_xor(acc.w, off);
    }

    if (sg == 0) {
        float rl = 1.0f / l;
        bf16x4 ov = { (__bf16)(acc.x * rl), (__bf16)(acc.y * rl),
                      (__bf16)(acc.z * rl), (__bf16)(acc.w * rl) };
        *(bf16x4*)(o + (size_t)pos * 192 + head * 32 + lane * 4) = ov;
    }
}

__global__ __launch_bounds__(256) void fused(
    const float* __restrict__ x, const float* __restrict__ scale1,
    const float* __restrict__ n1_w1, const float* __restrict__ n1_b1,
    const float* __restrict__ n1_w2, const float* __restrict__ n1_b2,
    const float* __restrict__ qkv_w, const float* __restrict__ qkv_b,
    const float* __restrict__ proj_w, const float* __restrict__ proj_b,
    const float* __restrict__ scale2,
    const float* __restrict__ n2_w1, const float* __restrict__ n2_b1,
    const float* __restrict__ n2_w2, const float* __restrict__ n2_b2,
    const float* __restrict__ mlp_w1, const float* __restrict__ mlp_b1,
    const float* __restrict__ mlp_w2, const float* __restrict__ mlp_b2,
    float* __restrict__ ws, float* __restrict__ x2)
{
    __shared__ __align__(16) char smraw[51200];   // GEMM al|bl; convx/stats reuse
    __bf16* al  = (__bf16*)smraw;
    __bf16* bl  = al + 64 * 200;
    float*  smf = (float*)smraw;

    float*  q_buf   = ws;
    __bf16* kv_buf  = (__bf16*)(ws + 786432);
    __bf16* xb      = (__bf16*)(ws + 2359296);
    __bf16* o_attn  = (__bf16*)(ws + 2752512);
    __bf16* qkv_wb  = (__bf16*)(ws + 3145728);
    __bf16* proj_wb = qkv_wb + 110592;
    __bf16* m1_wb   = proj_wb + 36864;
    __bf16* m2_wb   = m1_wb + 147456;
    float*  sums1   = ws + 3366912;
    float*  sumsq1  = ws + 3367104;
    float*  sums2   = ws + 3367296;
    float*  sumsq2  = ws + 3367488;
    __bf16* n1w1b   = (__bf16*)(ws + 3367680);
    __bf16* n1w2b   = n1w1b + 73728;
    __bf16* n2w1b   = n1w2b + 73728;
    __bf16* n2w2b   = n2w1b + 73728;
    unsigned* bar   = (unsigned*)(ws + 3515136);   // 4096 uints
    __bf16* m_buf   = (__bf16*)(ws + 3520512);     // [4096][768] bf16 (un-aliased)
    __bf16* xb2     = (__bf16*)(ws + 5093376);     // [4096][192] bf16 (convx2 out)

    int bid = blockIdx.x;
    int t   = threadIdx.x;

    // real XCD id (HW_REG_XCC_ID = id 20, offset 0, width 32 -> imm 63508)
    int xcc = __builtin_amdgcn_s_getreg(63508) & 7;

    // ---- population count + maintenance-free pre-barrier ----
    if (t == 0)
        __hip_atomic_fetch_add(bar + xcc * 16, 1u, __ATOMIC_RELAXED,
                               __HIP_MEMORY_SCOPE_AGENT);
    pre_sync(bar, bid & 7);
    unsigned myPop = 0, nx = 0;
    if (t == 0) {
        myPop = __hip_atomic_load(bar + xcc * 16, __ATOMIC_RELAXED,
                                  __HIP_MEMORY_SCOPE_AGENT);
        #pragma unroll
        for (int xi = 0; xi < 8; xi++)
            nx += (__hip_atomic_load(bar + xi * 16, __ATOMIC_RELAXED,
                                     __HIP_MEMORY_SCOPE_AGENT) > 0u) ? 1u : 0u;
    }

    // ---- phase A: weight conversions + stats(x) + zero stats2 ----
    for (int u = bid; u < 913; u += NB) {
        if      (u < 108) conv_unit(qkv_w,  qkv_wb, u);
        else if (u < 144) conv_unit(proj_w, proj_wb, u - 108);
        else if (u < 288) conv_unit(mlp_w1, m1_wb, u - 144);
        else if (u < 432) conv_unit(mlp_w2, m2_wb, u - 288);
        else if (u < 504) conv_unit(n1_w1,  n1w1b, u - 432);
        else if (u < 576) conv_unit(n1_w2,  n1w2b, u - 504);
        else if (u < 648) conv_unit(n2_w1,  n2w1b, u - 576);
        else if (u < 720) conv_unit(n2_w2,  n2w2b, u - 648);
        else if (u < 912) stats_unit(smf, x, sums1, sumsq1, u - 720);
        else {
            if (t < 192) {   // coherent-point zeros (E atomicAdds onto them)
                __hip_atomic_store(&sums2[t], 0.f, __ATOMIC_RELAXED,
                                   __HIP_MEMORY_SCOPE_AGENT);
                __hip_atomic_store(&sumsq2[t], 0.f, __ATOMIC_RELAXED,
                                   __HIP_MEMORY_SCOPE_AGENT);
            }
        }
    }
    grid_sync(bar, 0, xcc, myPop, nx);

    // ---- phase B: convx1 ----
    if (bid < 256)
        convx_body(smf, x, sums1, sumsq1, scale1, n1w1b, n1_b1, n1w2b, n1_b2, xb, bid * 16);
    grid_sync(bar, 1, xcc, myPop, nx);

    // ---- phase C: qkv GEMM (576 tiles) ----
    for (int tile = bid; tile < 576; tile += NB)
        gemm_tile<192, 0>(al, bl, tile & 63, tile >> 6, qkv_wb, qkv_b, xb,
                          (void*)q_buf, nullptr, 576, kv_buf, nullptr, nullptr);
    grid_sync(bar, 2, xcc, myPop, nx);

    // ---- phase D: attention (XCD-local mapping: block b -> slab b%8) ----
    {
        int base = (bid & 7) * 384 + (bid >> 3) * 6;
        for (int i = 0; i < 6; i++)
            attn_unit(q_buf, kv_buf, o_attn, base + i);
    }
    grid_sync(bar, 3, xcc, myPop, nx);

    // ---- phase E: proj GEMM + residual + fused stats atomics (192 tiles) ----
    if (bid < 192)
        gemm_tile<192, 4>(al, bl, bid & 63, bid >> 6, proj_wb, proj_b, o_attn,
                          (void*)x2, x, 192, nullptr, sums2, sumsq2);
    grid_sync(bar, 4, xcc, myPop, nx);

    // ---- phase F: convx2 (-> xb2, fresh region) ----
    if (bid < 256)
        convx_body(smf, x2, sums2, sumsq2, scale2, n2w1b, n2_b1, n2w2b, n2_b2, xb2, bid * 16);
    grid_sync(bar, 5, xcc, myPop, nx);

    // ---- phase G: mlp1 GEMM (768 tiles, gelu -> m_buf bf16^T) ----
    for (int tile = bid; tile < 768; tile += NB)
        gemm_tile<192, 3>(al, bl, tile & 63, tile >> 6, m1_wb, mlp_b1, xb2,
                          (void*)m_buf, nullptr, 768, nullptr, nullptr, nullptr);
    grid_sync(bar, 6, xcc, myPop, nx);

    // ---- phase H: mlp2 GEMM + residual (in-place x2) ----
    if (bid < 192)
        gemm_tile<768, 2>(al, bl, bid & 63, bid >> 6, m2_wb, mlp_b2, m_buf,
                          (void*)x2, x2, 192, nullptr, nullptr, nullptr);
}

// ---------------------------------------------------------------------------
extern "C" void kernel_launch(void* const* d_in, const int* in_sizes, int n_in,
                              void* d_out, int out_size, void* d_ws, size_t ws_size,
                              hipStream_t stream)
{
    const float* x      = (const float*)d_in[0];
    const float* scale1 = (const float*)d_in[1];
    const float* n1_w1  = (const float*)d_in[2];
    const float* n1_b1  = (const float*)d_in[3];
    const float* n1_w2  = (const float*)d_in[4];
    const float* n1_b2  = (const float*)d_in[5];
    const float* qkv_w  = (const float*)d_in[6];
    const float* qkv_b  = (const float*)d_in[7];
    const float* proj_w = (const float*)d_in[8];
    const float* proj_b = (const float*)d_in[9];
    const float* scale2 = (const float*)d_in[10];
    const float* n2_w1  = (const float*)d_in[11];
    const float* n2_b1  = (const float*)d_in[12];
    const float* n2_w2  = (const float*)d_in[13];
    const float* n2_b2  = (const float*)d_in[14];
    const float* mlp_w1 = (const float*)d_in[15];
    const float* mlp_b1 = (const float*)d_in[16];
    const float* mlp_w2 = (const float*)d_in[17];
    const float* mlp_b2 = (const float*)d_in[18];

    float* ws = (float*)d_ws;
    float* x2 = (float*)d_out;

    // zero pops + pre-barrier + 7 data barriers: 4096 uints = 16KB per replay
    hipMemsetAsync(ws + 3515136, 0, 4096 * sizeof(unsigned), stream);

    fused<<<NB, 256, 0, stream>>>(x, scale1, n1_w1, n1_b1, n1_w2, n1_b2,
                                  qkv_w, qkv_b, proj_w, proj_b,
                                  scale2, n2_w1, n2_b1, n2_w2, n2_b2,
                                  mlp_w1, mlp_b1, mlp_w2, mlp_b2,
                                  ws, x2);
}